// Round 10
// baseline (2434.430 us; speedup 1.0000x reference)
//
#include <hip/hip_runtime.h>
#include <hip/hip_bf16.h>
#include <stdint.h>

typedef __attribute__((ext_vector_type(8))) short short8;
typedef __attribute__((ext_vector_type(4))) float floatx4;

#define B_ 64
#define T_ 256
#define H_ 1024
#define LATENT_ 256
#define P_ 128
#define BH_ (B_ * H_)
#define MFMA_(a, b, c) __builtin_amdgcn_mfma_f32_16x16x32_bf16(a, b, c, 0, 0, 0)
// LDS column swizzle for pbuf (multiplier 4: MFMA-phase writes alias exactly
// 2-way = free; 5 regressed conflicts 5.1e7->8.5e7 in R11).
#define PBI(n, row) (((n) + 4 * (row)) & 31)

// LDS: pbuf only (ALL B-fragments registerized). 64 KB.
#define LDS_TOTAL 65536

// ---- Sync v8 (R18): 16-byte marker lines, arrive==publish ----
// Learned rules: RMW chains ok only if line never polled; spin-poll only on
// (near-)single-writer lines; poll-on-RMW-line ~+3us (R12,R14); many-readers
// x many-lines worst (R9); never issue bulk loads before an expected-instant
// spin (vmcnt FIFO drain, R16). v8 removes the last dependent hop: producer
// hblk&15 byte-stores 0xFF into line (lay,slot,group,rep) after its drain;
// consumer lane0 polls 16 bytes (2 u64 loads) until all-ones. No fetch_add,
// no last-arriver branch on an RMW result. 2 replicas cap pollers/line ~64.
#define SLOTS 258
// line index within (lay,slot): g*2+rep, g in [0,8). 32 lines reserved.
#define MRK(lay, slot, g, rep) \
    ((((size_t)(lay) * SLOTS + (slot)) * 32 + 2 * (g) + (rep)) * 16)
#define CNTW (2 * SLOTS * 32 * 16)

// Block-major h layout: element offset of (b, j) = ((j>>3)*64 + b)*8 + (j&7).

__device__ __forceinline__ float sigmoidf_(float x) {
    return 1.0f / (1.0f + __expf(-x));
}
__device__ __forceinline__ float tanh_fast(float x) {
    float e = __expf(2.0f * x);
    return 1.0f - 2.0f / (e + 1.0f);
}

// ---------------------------------------------------------------------------
__global__ __launch_bounds__(256) void cvt_f2b(
    const float* __restrict__ src, __hip_bfloat16* __restrict__ dst, int n)
{
    int i = (blockIdx.x * 256 + threadIdx.x) * 4;
    if (i < n) {
        float4 v = *(const float4*)(src + i);
        dst[i + 0] = __float2bfloat16(v.x);
        dst[i + 1] = __float2bfloat16(v.y);
        dst[i + 2] = __float2bfloat16(v.z);
        dst[i + 3] = __float2bfloat16(v.w);
    }
}

// h0 -> the two t=-1 slots (block-major); init markers (slot0 = all-ones).
__global__ __launch_bounds__(256) void h0_kernel(
    const float* __restrict__ z,
    const float* __restrict__ fw,
    const float* __restrict__ fb,
    __hip_bfloat16* __restrict__ h1dst,
    __hip_bfloat16* __restrict__ h2dst,
    unsigned* __restrict__ cnt)
{
    int idx = blockIdx.x * 256 + threadIdx.x;      // 0..65535
    for (int i = idx; i < CNTW; i += 65536) {
        int line = i >> 4;
        int word = i & 15;
        int li   = line & 31;
        int slot = (line >> 5) % SLOTS;
        // marker lines are li in [0,16): bytes 0..15 live in words 0..3
        cnt[i] = (slot == 0 && li < 16 && word < 4) ? 0xFFFFFFFFu : 0u;
    }
    int b = idx >> 10, j = idx & 1023;
    const float* zp = z + b * LATENT_;
    const float* wp = fw + j * LATENT_;
    float acc = fb[j];
    for (int k = 0; k < LATENT_; k += 4) {
        float4 zv = *(const float4*)(zp + k);
        float4 wv = *(const float4*)(wp + k);
        acc += zv.x * wv.x + zv.y * wv.y + zv.z * wv.z + zv.w * wv.w;
    }
    __hip_bfloat16 hb = __float2bfloat16(acc);
    int off = ((j >> 3) * 64 + b) * 8 + (j & 7);   // block-major
    h1dst[off] = hb;
    h2dst[off] = hb;
}

struct PParams {
    const __hip_bfloat16 *tseqb, *stokb;
    const __hip_bfloat16 *Wih0b, *Whh0b, *Wih1b, *Whh1b, *owb;
    const float *bih0, *bhh0, *bih1, *bhh1, *ob;
    __hip_bfloat16 *h1seq;    // T+1 slots, write-once per t (slot t+1)
    __hip_bfloat16 *h2seq;    // T+1 slots
    float* out;               // (B, T, P)
    unsigned* cnt;            // marker lines (MRK)
};

// ---------------------------------------------------------------------------
// Persistent dataflow LSTM. 256 blocks x 512 threads (8 waves), 1 block/CU.
//   blocks   0..127 : layer-1 step t=phase-1 ; blocks 128..255 : layer-0 t=phase
// R18 = R17 schedule + (a) Wih1 B-rows registerized (they are loop-invariant;
// kills 64KB/block/phase of L2 stream + their consume-path latency) and
// (b) sync v8 marker lines (arrive==publish, one LLC hop fewer per phase).
// ---------------------------------------------------------------------------
__global__ __launch_bounds__(512, 2) void lstm_persistent(PParams p)
{
    extern __shared__ char dynlds[];
    float (*pbuf)[64][32] = (float (*)[64][32])dynlds;

    const int tid  = threadIdx.x;
    const int bid  = blockIdx.x;
    const int wv   = tid >> 6;
    const int l    = tid & 63;
    const int l15  = l & 15;
    const int quad = l >> 4;
    const int ks   = quad * 8;
    const bool isL1 = bid < 128;
    const int colbase = (isL1 ? bid : bid - 128) * 8;
    const int hblk = colbase >> 3;     // own column-block index (0..127)
    const int row0 = ((l15 >> 3)    ) * H_ + colbase + (l15 & 7);
    const int row1 = ((l15 >> 3) + 2) * H_ + colbase + (l15 & 7);

    auto h1slot = [&](int t) { return p.h1seq + (size_t)(t + 1) * BH_; };
    auto h2slot = [&](int t) { return p.h2seq + (size_t)(t + 1) * BH_; };

    // lane0-of-wave polls its group's 16-byte marker line (byte writers only).
    auto wspin = [&](int lay, int slot) {
        if (l == 0) {
            const unsigned long long* m8 =
                (const unsigned long long*)(p.cnt + MRK(lay, slot, wv, bid & 1));
            for (;;) {
                unsigned long long a = __hip_atomic_load(m8,
                                        __ATOMIC_RELAXED, __HIP_MEMORY_SCOPE_AGENT);
                unsigned long long b2 = __hip_atomic_load(m8 + 1,
                                        __ATOMIC_RELAXED, __HIP_MEMORY_SCOPE_AGENT);
                if ((a & b2) == ~0ull) break;
                __builtin_amdgcn_s_sleep(2);
            }
        }
        asm volatile("" ::: "memory");
    };

    // ---- registerized B-fragments (ALL loop-invariant) ----
    short8 bh0r[4], bh1r[4];           // Whh rows (gates {i,f} / {g,o})
    {
        const short* Wh = (const short*)(isL1 ? p.Whh1b : p.Whh0b);
#pragma unroll
        for (int c = 0; c < 4; ++c) {
            int kR = wv * 16 + c * 4 + quad;
            bh0r[c] = *(const short8*)(Wh + (long)row0 * H_ + kR * 8);
            bh1r[c] = *(const short8*)(Wh + (long)row1 * H_ + kR * 8);
        }
    }
    short8 bw0r[4], bw1r[4];           // L1: Wih1 rows (R18: invariant!)
    if (isL1) {
        const short* w0 = (const short*)p.Wih1b + (long)row0 * H_;
        const short* w1 = (const short*)p.Wih1b + (long)row1 * H_;
#pragma unroll
        for (int c = 0; c < 4; ++c) {
            int kR = wv * 16 + c * 4 + quad;
            bw0r[c] = *(const short8*)(w0 + kR * 8);
            bw1r[c] = *(const short8*)(w1 + kR * 8);
        }
    }
    short8 bx0r, bx1r;                 // L0 x-part (wv<4 only)
    if (!isL1 && wv < 4) {
        const short* Wx = (const short*)p.Wih0b;
        int kcx = wv * 4 + quad;
        bx0r = *(const short8*)(Wx + (long)row0 * P_ + kcx * 8);
        bx1r = *(const short8*)(Wx + (long)row1 * P_ + kcx * 8);
    }

    // Cell duty: all 512 threads, one cell each (b = tid>>3, col = tid&7).
    const int cm  = tid >> 3;
    const int c0  = tid & 7;
    const int cj0 = colbase + c0;
    const float* bi = isL1 ? p.bih1 : p.bih0;
    const float* bh = isL1 ? p.bhh1 : p.bhh0;
    float bs[4];
#pragma unroll
    for (int g = 0; g < 4; ++g)
        bs[g] = bi[g * H_ + cj0] + bh[g * H_ + cj0];
    float creg = 0.0f;

    const int lay = isL1 ? 1 : 0;
    const int agrp = hblk >> 4;        // marker group (0..7)
    const int mbyte = hblk & 15;       // marker byte within the line

    for (int phase = 0; phase <= T_; ++phase) {
        const bool doGemm = isL1 ? (phase >= 1) : (phase < T_);
        const int t = isL1 ? phase - 1 : phase;
        if (!doGemm) continue;

        floatx4 acc[8] = {};
        if (isL1) {
            // ---- h2 wait first: own chain = critical; pipe empty so polls
            //      are cheap; af2 issues the moment the marker completes ----
            wspin(1, phase - 1);
            const short* A2 = (const short*)h2slot(t - 1);
            short8 af2[16];
#pragma unroll
            for (int c = 0; c < 4; ++c)
#pragma unroll
                for (int mt = 0; mt < 4; ++mt) {
                    int kR = wv * 16 + c * 4 + quad;
                    af2[c * 4 + mt] = *(const short8*)(A2 +
                        ((long)(kR * 64 + mt * 16 + l15) << 3));
                }
            // ---- h1 flag: L0 free-runs ahead -> instant ----
            wspin(0, phase);
            const short* A1 = (const short*)h1slot(t);
            short8 af1[16];
#pragma unroll
            for (int c = 0; c < 4; ++c)
#pragma unroll
                for (int mt = 0; mt < 4; ++mt) {
                    int kR = wv * 16 + c * 4 + quad;
                    af1[c * 4 + mt] = *(const short8*)(A1 +
                        ((long)(kR * 64 + mt * 16 + l15) << 3));
                }
            // h2 x Whh1 FIRST: needs only af2 (oldest in FIFO) + register B.
#pragma unroll
            for (int c = 0; c < 4; ++c) {
#pragma unroll
                for (int mt = 0; mt < 4; ++mt) {
                    acc[2 * mt]     = MFMA_(af2[c * 4 + mt], bh0r[c], acc[2 * mt]);
                    acc[2 * mt + 1] = MFMA_(af2[c * 4 + mt], bh1r[c], acc[2 * mt + 1]);
                }
            }
            // h1 x Wih1: af1 arrived during the h2-part; B in registers.
#pragma unroll
            for (int c = 0; c < 4; ++c) {
#pragma unroll
                for (int mt = 0; mt < 4; ++mt) {
                    acc[2 * mt]     = MFMA_(af1[c * 4 + mt], bw0r[c], acc[2 * mt]);
                    acc[2 * mt + 1] = MFMA_(af1[c * 4 + mt], bw1r[c], acc[2 * mt + 1]);
                }
            }
        } else {
            // ---- x prefetch (tiny, 4 loads) before the wait ----
            const short* Ax; long xstr;
            if (t == 0) { Ax = (const short*)p.stokb; xstr = 0; }
            else { Ax = (const short*)p.tseqb + (long)(t - 1) * P_; xstr = (long)T_ * P_; }
            short8 xf[4];
            if (wv < 4) {
#pragma unroll
                for (int mt = 0; mt < 4; ++mt)
                    xf[mt] = *(const short8*)(Ax + (long)(mt * 16 + l15) * xstr + wv * 32 + ks);
            }
            wspin(0, phase);
            const short* Ah = (const short*)h1slot(t - 1);
            short8 af[16];
#pragma unroll
            for (int c = 0; c < 4; ++c)
#pragma unroll
                for (int mt = 0; mt < 4; ++mt) {
                    int kR = wv * 16 + c * 4 + quad;
                    af[c * 4 + mt] = *(const short8*)(Ah +
                        ((long)(kR * 64 + mt * 16 + l15) << 3));
                }
            if (wv < 4) {   // x-part (B in registers, xf long arrived)
#pragma unroll
                for (int mt = 0; mt < 4; ++mt) {
                    acc[2 * mt]     = MFMA_(xf[mt], bx0r, acc[2 * mt]);
                    acc[2 * mt + 1] = MFMA_(xf[mt], bx1r, acc[2 * mt + 1]);
                }
            }
#pragma unroll
            for (int c = 0; c < 4; ++c) {
#pragma unroll
                for (int mt = 0; mt < 4; ++mt) {
                    acc[2 * mt]     = MFMA_(af[c * 4 + mt], bh0r[c], acc[2 * mt]);
                    acc[2 * mt + 1] = MFMA_(af[c * 4 + mt], bh1r[c], acc[2 * mt + 1]);
                }
            }
        }
        // C/D: col = lane&15, row = quad*4 + reg (+ mt*16)
#pragma unroll
        for (int mt = 0; mt < 4; ++mt)
#pragma unroll
            for (int nt = 0; nt < 2; ++nt)
#pragma unroll
                for (int r = 0; r < 4; ++r) {
                    int row = mt * 16 + quad * 4 + r;
                    pbuf[wv][row][PBI(nt * 16 + l15, row)] = acc[2 * mt + nt][r];
                }
        __syncthreads();

        // ---- cell: all 512 threads, one column each ----
        {
            float v[4];
#pragma unroll
            for (int g = 0; g < 4; ++g) v[g] = bs[g];
#pragma unroll
            for (int w2 = 0; w2 < 8; ++w2)
#pragma unroll
                for (int g = 0; g < 4; ++g)
                    v[g] += pbuf[w2][cm][PBI(8 * g + c0, cm)];
            float cn = sigmoidf_(v[1]) * creg + sigmoidf_(v[0]) * tanh_fast(v[2]);
            float hv = sigmoidf_(v[3]) * tanh_fast(cn);
            creg = cn;
            __hip_bfloat16* hdst = isL1 ? h2slot(t) : h1slot(t);
            __hip_bfloat16 hb = __float2bfloat16(hv);
            unsigned short hu = *(unsigned short*)&hb;
            __hip_atomic_store((unsigned short*)hdst + hblk * 512 + tid, hu,
                               __ATOMIC_RELAXED, __HIP_MEMORY_SCOPE_AGENT);
        }

        // __syncthreads drains each wave's vmcnt(0): h stores complete at LLC
        // before tid0's marker store (arrive == publish). Also fences pbuf.
        __syncthreads();
        if (tid == 0) {
            unsigned char* m0 = (unsigned char*)(p.cnt + MRK(lay, t + 1, agrp, 0));
            unsigned char* m1 = (unsigned char*)(p.cnt + MRK(lay, t + 1, agrp, 1));
            __hip_atomic_store(m0 + mbyte, (unsigned char)0xFF,
                               __ATOMIC_RELAXED, __HIP_MEMORY_SCOPE_AGENT);
            __hip_atomic_store(m1 + mbyte, (unsigned char)0xFF,
                               __ATOMIC_RELAXED, __HIP_MEMORY_SCOPE_AGENT);
        }
    }

    // ---- Post-loop output projection: one block per timestep t = bid ----
    {
        const int t = bid;
        if (tid == 0) {            // h2(t) complete: all 8 groups' markers
            for (int g = 0; g < 8; ++g) {
                const unsigned long long* m8 =
                    (const unsigned long long*)(p.cnt + MRK(1, t + 1, g, bid & 1));
                for (;;) {
                    unsigned long long a = __hip_atomic_load(m8,
                                            __ATOMIC_RELAXED, __HIP_MEMORY_SCOPE_AGENT);
                    unsigned long long b2 = __hip_atomic_load(m8 + 1,
                                            __ATOMIC_RELAXED, __HIP_MEMORY_SCOPE_AGENT);
                    if ((a & b2) == ~0ull) break;
                    __builtin_amdgcn_s_sleep(2);
                }
            }
        }
        asm volatile("" ::: "memory");
        __syncthreads();

        const int nh = wv >> 1, kh = wv & 1;
        const short* A  = (const short*)h2slot(t);
        const short* Wb = (const short*)p.owb;
        floatx4 oacc[8] = {};
        for (int c = 0; c < 16; ++c) {
            int kk = kh * 512 + c * 32 + ks;
            short8 b0 = *(const short8*)(Wb + (long)(nh * 32 + l15) * H_ + kk);
            short8 b1 = *(const short8*)(Wb + (long)(nh * 32 + 16 + l15) * H_ + kk);
#pragma unroll
            for (int mt = 0; mt < 4; ++mt) {
                short8 a = *(const short8*)(A +
                    ((long)((kh * 64 + c * 4 + quad) * 64 + mt * 16 + l15) << 3));
                oacc[2 * mt]     = MFMA_(a, b0, oacc[2 * mt]);
                oacc[2 * mt + 1] = MFMA_(a, b1, oacc[2 * mt + 1]);
            }
        }
#pragma unroll
        for (int mt = 0; mt < 4; ++mt)
#pragma unroll
            for (int nt = 0; nt < 2; ++nt)
#pragma unroll
                for (int r = 0; r < 4; ++r) {
                    int row = mt * 16 + quad * 4 + r;
                    pbuf[wv][row][PBI(nt * 16 + l15, row)] = oacc[2 * mt + nt][r];
                }
        __syncthreads();
        for (int i = tid; i < 64 * 128; i += 512) {
            int m = i >> 7, pp2 = i & 127;
            int nh2 = pp2 >> 5, pc = pp2 & 31;
            float v = pbuf[2 * nh2][m][PBI(pc, m)] + pbuf[2 * nh2 + 1][m][PBI(pc, m)]
                    + p.ob[pp2];
            p.out[(long)m * (T_ * P_) + (long)t * P_ + pp2] = sigmoidf_(v);
        }
    }
}

// ---------------------------------------------------------------------------
extern "C" void kernel_launch(void* const* d_in, const int* in_sizes, int n_in,
                              void* d_out, int out_size, void* d_ws, size_t ws_size,
                              hipStream_t stream) {
    const float* z    = (const float*)d_in[0];
    const float* tseq = (const float*)d_in[1];
    const float* fw   = (const float*)d_in[2];
    const float* fb   = (const float*)d_in[3];
    const float* stok = (const float*)d_in[4];
    const float* Wih0 = (const float*)d_in[5];
    const float* Whh0 = (const float*)d_in[6];
    const float* bih0 = (const float*)d_in[7];
    const float* bhh0 = (const float*)d_in[8];
    const float* Wih1 = (const float*)d_in[9];
    const float* Whh1 = (const float*)d_in[10];
    const float* bih1 = (const float*)d_in[11];
    const float* bhh1 = (const float*)d_in[12];
    const float* ow   = (const float*)d_in[13];
    const float* ob   = (const float*)d_in[14];
    float* out = (float*)d_out;

    // Workspace (~94 MB).
    const size_t FULLH = (size_t)(T_ + 1) * BH_ * 2;
    char* ws = (char*)d_ws;
    size_t off = 0;
    __hip_bfloat16* Wih0b = (__hip_bfloat16*)(ws + off); off += (size_t)4 * H_ * P_ * 2;
    __hip_bfloat16* Whh0b = (__hip_bfloat16*)(ws + off); off += (size_t)4 * H_ * H_ * 2;
    __hip_bfloat16* Wih1b = (__hip_bfloat16*)(ws + off); off += (size_t)4 * H_ * H_ * 2;
    __hip_bfloat16* Whh1b = (__hip_bfloat16*)(ws + off); off += (size_t)4 * H_ * H_ * 2;
    __hip_bfloat16* owb   = (__hip_bfloat16*)(ws + off); off += (size_t)P_ * H_ * 2;
    __hip_bfloat16* tseqb = (__hip_bfloat16*)(ws + off); off += (size_t)B_ * T_ * P_ * 2;
    __hip_bfloat16* stokb = (__hip_bfloat16*)(ws + off); off += 256;
    __hip_bfloat16* h1seq = (__hip_bfloat16*)(ws + off); off += FULLH;
    __hip_bfloat16* h2seq = (__hip_bfloat16*)(ws + off); off += FULLH;
    unsigned* cnt         = (unsigned*)(ws + off);       off += (size_t)CNTW * 4;

    auto cvt = [&](const float* s, __hip_bfloat16* d, int n) {
        hipLaunchKernelGGL(cvt_f2b, dim3((n / 4 + 255) / 256), dim3(256), 0, stream, s, d, n);
    };
    cvt(Wih0, Wih0b, 4 * H_ * P_);
    cvt(Whh0, Whh0b, 4 * H_ * H_);
    cvt(Wih1, Wih1b, 4 * H_ * H_);
    cvt(Whh1, Whh1b, 4 * H_ * H_);
    cvt(ow,   owb,   P_ * H_);
    cvt(tseq, tseqb, B_ * T_ * P_);
    cvt(stok, stokb, P_);

    // h0 into the t=-1 slots; init marker lines (slot0 preset complete).
    hipLaunchKernelGGL(h0_kernel, dim3(256), dim3(256), 0, stream,
                       z, fw, fb, h1seq, h2seq, cnt);

    PParams pp;
    pp.tseqb = tseqb; pp.stokb = stokb;
    pp.Wih0b = Wih0b; pp.Whh0b = Whh0b; pp.Wih1b = Wih1b; pp.Whh1b = Whh1b;
    pp.owb = owb;
    pp.bih0 = bih0; pp.bhh0 = bhh0; pp.bih1 = bih1; pp.bhh1 = bhh1; pp.ob = ob;
    pp.h1seq = h1seq; pp.h2seq = h2seq;
    pp.out = out;
    pp.cnt = cnt;

    hipFuncSetAttribute((const void*)lstm_persistent,
                        hipFuncAttributeMaxDynamicSharedMemorySize, LDS_TOTAL);
    void* args[] = { &pp };
    hipLaunchCooperativeKernel((void*)lstm_persistent, dim3(256), dim3(512),
                               args, LDS_TOTAL, stream);
}

// Round 11
// 1577.936 us; speedup vs baseline: 1.5428x; 1.5428x over previous
//
#include <hip/hip_runtime.h>
#include <hip/hip_bf16.h>
#include <stdint.h>

typedef __attribute__((ext_vector_type(8))) short short8;
typedef __attribute__((ext_vector_type(4))) float floatx4;

#define B_ 64
#define T_ 256
#define H_ 1024
#define LATENT_ 256
#define P_ 128
#define BH_ (B_ * H_)
#define MFMA_(a, b, c) __builtin_amdgcn_mfma_f32_16x16x32_bf16(a, b, c, 0, 0, 0)
// LDS column swizzle for pbuf (multiplier 4: MFMA-phase writes alias exactly
// 2-way = free; 5 regressed conflicts 5.1e7->8.5e7 in R11).
#define PBI(n, row) (((n) + 4 * (row)) & 31)

// LDS: pbuf only (ALL B-fragments registerized). 64 KB.
#define LDS_TOTAL 65536

// ---- Sync v7 (R15/R17, proven best; R18's marker lines REGRESSED) ----
// Rules: RMW chains depth<=32 fine IF the line is never polled; spin-poll
// ONLY on quiescent single-writer lines (R18 violated: 16 byte-writers on
// the polled line, +2us/phase); poll-on-RMW-line ~+3us (R12,R14);
// many-readers x many-lines worst (R9); loads in flight across a spin
// poison the polls (vmcnt FIFO, R16) - but loads CONSUMED before the spin
// are free (R19's lever).
#define SLOTS 258
#define ARR(lay, slot, g) \
    ((((size_t)(lay) * SLOTS + (slot)) * 32 + (g)) * 16)
#define FLG(lay, slot, g, r) \
    ((((size_t)(lay) * SLOTS + (slot)) * 32 + 8 + 2 * (g) + (r)) * 16)
#define CNTW (2 * SLOTS * 32 * 16)

// Block-major h layout: element offset of (b, j) = ((j>>3)*64 + b)*8 + (j&7).

__device__ __forceinline__ float sigmoidf_(float x) {
    return 1.0f / (1.0f + __expf(-x));
}
__device__ __forceinline__ float tanh_fast(float x) {
    float e = __expf(2.0f * x);
    return 1.0f - 2.0f / (e + 1.0f);
}

// ---------------------------------------------------------------------------
__global__ __launch_bounds__(256) void cvt_f2b(
    const float* __restrict__ src, __hip_bfloat16* __restrict__ dst, int n)
{
    int i = (blockIdx.x * 256 + threadIdx.x) * 4;
    if (i < n) {
        float4 v = *(const float4*)(src + i);
        dst[i + 0] = __float2bfloat16(v.x);
        dst[i + 1] = __float2bfloat16(v.y);
        dst[i + 2] = __float2bfloat16(v.z);
        dst[i + 3] = __float2bfloat16(v.w);
    }
}

// h0 -> the two t=-1 slots (block-major); init sync words (slot0 flags = 1).
__global__ __launch_bounds__(256) void h0_kernel(
    const float* __restrict__ z,
    const float* __restrict__ fw,
    const float* __restrict__ fb,
    __hip_bfloat16* __restrict__ h1dst,
    __hip_bfloat16* __restrict__ h2dst,
    unsigned* __restrict__ cnt)
{
    int idx = blockIdx.x * 256 + threadIdx.x;      // 0..65535
    for (int i = idx; i < CNTW; i += 65536) {
        int line = i >> 4;
        int li   = line & 31;
        int slot = (line >> 5) % SLOTS;
        cnt[i] = ((i & 15) == 0 && li >= 8 && li < 24 && slot == 0) ? 1u : 0u;
    }
    int b = idx >> 10, j = idx & 1023;
    const float* zp = z + b * LATENT_;
    const float* wp = fw + j * LATENT_;
    float acc = fb[j];
    for (int k = 0; k < LATENT_; k += 4) {
        float4 zv = *(const float4*)(zp + k);
        float4 wv = *(const float4*)(wp + k);
        acc += zv.x * wv.x + zv.y * wv.y + zv.z * wv.z + zv.w * wv.w;
    }
    __hip_bfloat16 hb = __float2bfloat16(acc);
    int off = ((j >> 3) * 64 + b) * 8 + (j & 7);   // block-major
    h1dst[off] = hb;
    h2dst[off] = hb;
}

struct PParams {
    const __hip_bfloat16 *tseqb, *stokb;
    const __hip_bfloat16 *Wih0b, *Whh0b, *Wih1b, *Whh1b, *owb;
    const float *bih0, *bhh0, *bih1, *bhh1, *ob;
    __hip_bfloat16 *h1seq;    // T+1 slots, write-once per t (slot t+1)
    __hip_bfloat16 *h2seq;    // T+1 slots
    float* out;               // (B, T, P)
    unsigned* cnt;            // sync words (ARR/FLG)
};

// ---------------------------------------------------------------------------
// Persistent dataflow LSTM. 256 blocks x 512 threads (8 waves), 1 block/CU.
//   blocks   0..127 : layer-1 step t=phase-1 ; blocks 128..255 : layer-0 t=phase
// R19: the true recurrence is only the h2 (resp. h1) half of each GEMM.
// The other half's dependency (h1 for L1; x for L0) is ready EARLY (L0
// free-runs ahead; x is static). So: load AND CONSUME that half before the
// binding wspin - the MFMAs' waitcnts drain vmcnt, keeping polls clean
// (R16's poison was loads left in flight). Post-wait critical work shrinks
// to af2-stream + 64 MFMAs + pbuf + cell + publish.
// ---------------------------------------------------------------------------
__global__ __launch_bounds__(512, 2) void lstm_persistent(PParams p)
{
    extern __shared__ char dynlds[];
    float (*pbuf)[64][32] = (float (*)[64][32])dynlds;

    const int tid  = threadIdx.x;
    const int bid  = blockIdx.x;
    const int wv   = tid >> 6;
    const int l    = tid & 63;
    const int l15  = l & 15;
    const int quad = l >> 4;
    const int ks   = quad * 8;
    const bool isL1 = bid < 128;
    const int colbase = (isL1 ? bid : bid - 128) * 8;
    const int hblk = colbase >> 3;     // own column-block index (0..127)
    const int row0 = ((l15 >> 3)    ) * H_ + colbase + (l15 & 7);
    const int row1 = ((l15 >> 3) + 2) * H_ + colbase + (l15 & 7);

    auto h1slot = [&](int t) { return p.h1seq + (size_t)(t + 1) * BH_; };
    auto h2slot = [&](int t) { return p.h2seq + (size_t)(t + 1) * BH_; };

    // lane0-of-wave polls its group's flag (quiescent single-writer line).
    auto wspin = [&](int lay, int slot) {
        if (l == 0) {
            const unsigned* cf = p.cnt + FLG(lay, slot, wv, bid & 1);
            while (__hip_atomic_load(cf, __ATOMIC_RELAXED,
                                     __HIP_MEMORY_SCOPE_AGENT) == 0u)
                __builtin_amdgcn_s_sleep(2);
        }
        asm volatile("" ::: "memory");
    };

    // ---- registerized B-fragments (ALL loop-invariant) ----
    short8 bh0r[4], bh1r[4];           // Whh rows (gates {i,f} / {g,o})
    {
        const short* Wh = (const short*)(isL1 ? p.Whh1b : p.Whh0b);
#pragma unroll
        for (int c = 0; c < 4; ++c) {
            int kR = wv * 16 + c * 4 + quad;
            bh0r[c] = *(const short8*)(Wh + (long)row0 * H_ + kR * 8);
            bh1r[c] = *(const short8*)(Wh + (long)row1 * H_ + kR * 8);
        }
    }
    short8 bw0r[4], bw1r[4];           // L1: Wih1 rows (invariant)
    if (isL1) {
        const short* w0 = (const short*)p.Wih1b + (long)row0 * H_;
        const short* w1 = (const short*)p.Wih1b + (long)row1 * H_;
#pragma unroll
        for (int c = 0; c < 4; ++c) {
            int kR = wv * 16 + c * 4 + quad;
            bw0r[c] = *(const short8*)(w0 + kR * 8);
            bw1r[c] = *(const short8*)(w1 + kR * 8);
        }
    }
    short8 bx0r, bx1r;                 // L0 x-part (wv<4 only)
    if (!isL1 && wv < 4) {
        const short* Wx = (const short*)p.Wih0b;
        int kcx = wv * 4 + quad;
        bx0r = *(const short8*)(Wx + (long)row0 * P_ + kcx * 8);
        bx1r = *(const short8*)(Wx + (long)row1 * P_ + kcx * 8);
    }

    // Cell duty: all 512 threads, one cell each (b = tid>>3, col = tid&7).
    const int cm  = tid >> 3;
    const int c0  = tid & 7;
    const int cj0 = colbase + c0;
    const float* bi = isL1 ? p.bih1 : p.bih0;
    const float* bh = isL1 ? p.bhh1 : p.bhh0;
    float bs[4];
#pragma unroll
    for (int g = 0; g < 4; ++g)
        bs[g] = bi[g * H_ + cj0] + bh[g * H_ + cj0];
    float creg = 0.0f;

    const int lay = isL1 ? 1 : 0;
    const int agrp = hblk >> 4;        // arrival group (0..7)

    for (int phase = 0; phase <= T_; ++phase) {
        const bool doGemm = isL1 ? (phase >= 1) : (phase < T_);
        const int t = isL1 ? phase - 1 : phase;
        if (!doGemm) continue;

        floatx4 acc[8] = {};
        if (isL1) {
            // ==== PRE-WAIT half: h1 x Wih1 (h1 flag set early, L0 ahead) ====
            wspin(0, phase);
            const short* A1 = (const short*)h1slot(t);
            short8 af1[16];
#pragma unroll
            for (int c = 0; c < 4; ++c)
#pragma unroll
                for (int mt = 0; mt < 4; ++mt) {
                    int kR = wv * 16 + c * 4 + quad;
                    af1[c * 4 + mt] = *(const short8*)(A1 +
                        ((long)(kR * 64 + mt * 16 + l15) << 3));
                }
            // Consume af1 NOW (B in registers): the MFMAs' waitcnts drain
            // vmcnt, so the binding polls below are clean.
#pragma unroll
            for (int c = 0; c < 4; ++c) {
#pragma unroll
                for (int mt = 0; mt < 4; ++mt) {
                    acc[2 * mt]     = MFMA_(af1[c * 4 + mt], bw0r[c], acc[2 * mt]);
                    acc[2 * mt + 1] = MFMA_(af1[c * 4 + mt], bw1r[c], acc[2 * mt + 1]);
                }
            }
            // ==== BINDING wait: own-chain h2; pipe drained ====
            wspin(1, phase - 1);
            const short* A2 = (const short*)h2slot(t - 1);
            short8 af2[16];
#pragma unroll
            for (int c = 0; c < 4; ++c)
#pragma unroll
                for (int mt = 0; mt < 4; ++mt) {
                    int kR = wv * 16 + c * 4 + quad;
                    af2[c * 4 + mt] = *(const short8*)(A2 +
                        ((long)(kR * 64 + mt * 16 + l15) << 3));
                }
            // h2 x Whh1 (register B): the only post-wait compute.
#pragma unroll
            for (int c = 0; c < 4; ++c) {
#pragma unroll
                for (int mt = 0; mt < 4; ++mt) {
                    acc[2 * mt]     = MFMA_(af2[c * 4 + mt], bh0r[c], acc[2 * mt]);
                    acc[2 * mt + 1] = MFMA_(af2[c * 4 + mt], bh1r[c], acc[2 * mt + 1]);
                }
            }
        } else {
            // ==== PRE-WAIT half: x x Wih0 (static input) ====
            const short* Ax; long xstr;
            if (t == 0) { Ax = (const short*)p.stokb; xstr = 0; }
            else { Ax = (const short*)p.tseqb + (long)(t - 1) * P_; xstr = (long)T_ * P_; }
            if (wv < 4) {
                short8 xf[4];
#pragma unroll
                for (int mt = 0; mt < 4; ++mt)
                    xf[mt] = *(const short8*)(Ax + (long)(mt * 16 + l15) * xstr + wv * 32 + ks);
#pragma unroll
                for (int mt = 0; mt < 4; ++mt) {
                    acc[2 * mt]     = MFMA_(xf[mt], bx0r, acc[2 * mt]);
                    acc[2 * mt + 1] = MFMA_(xf[mt], bx1r, acc[2 * mt + 1]);
                }
            }
            // ==== BINDING wait: own-chain h1 ====
            wspin(0, phase);
            const short* Ah = (const short*)h1slot(t - 1);
            short8 af[16];
#pragma unroll
            for (int c = 0; c < 4; ++c)
#pragma unroll
                for (int mt = 0; mt < 4; ++mt) {
                    int kR = wv * 16 + c * 4 + quad;
                    af[c * 4 + mt] = *(const short8*)(Ah +
                        ((long)(kR * 64 + mt * 16 + l15) << 3));
                }
#pragma unroll
            for (int c = 0; c < 4; ++c) {
#pragma unroll
                for (int mt = 0; mt < 4; ++mt) {
                    acc[2 * mt]     = MFMA_(af[c * 4 + mt], bh0r[c], acc[2 * mt]);
                    acc[2 * mt + 1] = MFMA_(af[c * 4 + mt], bh1r[c], acc[2 * mt + 1]);
                }
            }
        }
        // C/D: col = lane&15, row = quad*4 + reg (+ mt*16)
#pragma unroll
        for (int mt = 0; mt < 4; ++mt)
#pragma unroll
            for (int nt = 0; nt < 2; ++nt)
#pragma unroll
                for (int r = 0; r < 4; ++r) {
                    int row = mt * 16 + quad * 4 + r;
                    pbuf[wv][row][PBI(nt * 16 + l15, row)] = acc[2 * mt + nt][r];
                }
        __syncthreads();

        // ---- cell: all 512 threads, one column each ----
        {
            float v[4];
#pragma unroll
            for (int g = 0; g < 4; ++g) v[g] = bs[g];
#pragma unroll
            for (int w2 = 0; w2 < 8; ++w2)
#pragma unroll
                for (int g = 0; g < 4; ++g)
                    v[g] += pbuf[w2][cm][PBI(8 * g + c0, cm)];
            float cn = sigmoidf_(v[1]) * creg + sigmoidf_(v[0]) * tanh_fast(v[2]);
            float hv = sigmoidf_(v[3]) * tanh_fast(cn);
            creg = cn;
            __hip_bfloat16* hdst = isL1 ? h2slot(t) : h1slot(t);
            __hip_bfloat16 hb = __float2bfloat16(hv);
            unsigned short hu = *(unsigned short*)&hb;
            __hip_atomic_store((unsigned short*)hdst + hblk * 512 + tid, hu,
                               __ATOMIC_RELAXED, __HIP_MEMORY_SCOPE_AGENT);
        }

        // __syncthreads drains each wave's vmcnt(0): h stores complete at LLC.
        // Also fences cell's pbuf reads vs next phase's pbuf writes.
        __syncthreads();
        if (tid == 0) {
            unsigned old = __hip_atomic_fetch_add(
                p.cnt + ARR(lay, t + 1, agrp), 1u,
                __ATOMIC_RELAXED, __HIP_MEMORY_SCOPE_AGENT);
            if (old == 15u) {   // last arriver of the group publishes
                __hip_atomic_store(p.cnt + FLG(lay, t + 1, agrp, 0), 1u,
                                   __ATOMIC_RELAXED, __HIP_MEMORY_SCOPE_AGENT);
                __hip_atomic_store(p.cnt + FLG(lay, t + 1, agrp, 1), 1u,
                                   __ATOMIC_RELAXED, __HIP_MEMORY_SCOPE_AGENT);
            }
        }
    }

    // ---- Post-loop output projection: one block per timestep t = bid ----
    {
        const int t = bid;
        if (tid == 0) {            // h2(t) complete: all 8 groups' flags
            for (int g = 0; g < 8; ++g) {
                const unsigned* cf = p.cnt + FLG(1, t + 1, g, bid & 1);
                while (__hip_atomic_load(cf, __ATOMIC_RELAXED,
                                         __HIP_MEMORY_SCOPE_AGENT) == 0u)
                    __builtin_amdgcn_s_sleep(2);
            }
        }
        asm volatile("" ::: "memory");
        __syncthreads();

        const int nh = wv >> 1, kh = wv & 1;
        const short* A  = (const short*)h2slot(t);
        const short* Wb = (const short*)p.owb;
        floatx4 oacc[8] = {};
        for (int c = 0; c < 16; ++c) {
            int kk = kh * 512 + c * 32 + ks;
            short8 b0 = *(const short8*)(Wb + (long)(nh * 32 + l15) * H_ + kk);
            short8 b1 = *(const short8*)(Wb + (long)(nh * 32 + 16 + l15) * H_ + kk);
#pragma unroll
            for (int mt = 0; mt < 4; ++mt) {
                short8 a = *(const short8*)(A +
                    ((long)((kh * 64 + c * 4 + quad) * 64 + mt * 16 + l15) << 3));
                oacc[2 * mt]     = MFMA_(a, b0, oacc[2 * mt]);
                oacc[2 * mt + 1] = MFMA_(a, b1, oacc[2 * mt + 1]);
            }
        }
#pragma unroll
        for (int mt = 0; mt < 4; ++mt)
#pragma unroll
            for (int nt = 0; nt < 2; ++nt)
#pragma unroll
                for (int r = 0; r < 4; ++r) {
                    int row = mt * 16 + quad * 4 + r;
                    pbuf[wv][row][PBI(nt * 16 + l15, row)] = oacc[2 * mt + nt][r];
                }
        __syncthreads();
        for (int i = tid; i < 64 * 128; i += 512) {
            int m = i >> 7, pp2 = i & 127;
            int nh2 = pp2 >> 5, pc = pp2 & 31;
            float v = pbuf[2 * nh2][m][PBI(pc, m)] + pbuf[2 * nh2 + 1][m][PBI(pc, m)]
                    + p.ob[pp2];
            p.out[(long)m * (T_ * P_) + (long)t * P_ + pp2] = sigmoidf_(v);
        }
    }
}

// ---------------------------------------------------------------------------
extern "C" void kernel_launch(void* const* d_in, const int* in_sizes, int n_in,
                              void* d_out, int out_size, void* d_ws, size_t ws_size,
                              hipStream_t stream) {
    const float* z    = (const float*)d_in[0];
    const float* tseq = (const float*)d_in[1];
    const float* fw   = (const float*)d_in[2];
    const float* fb   = (const float*)d_in[3];
    const float* stok = (const float*)d_in[4];
    const float* Wih0 = (const float*)d_in[5];
    const float* Whh0 = (const float*)d_in[6];
    const float* bih0 = (const float*)d_in[7];
    const float* bhh0 = (const float*)d_in[8];
    const float* Wih1 = (const float*)d_in[9];
    const float* Whh1 = (const float*)d_in[10];
    const float* bih1 = (const float*)d_in[11];
    const float* bhh1 = (const float*)d_in[12];
    const float* ow   = (const float*)d_in[13];
    const float* ob   = (const float*)d_in[14];
    float* out = (float*)d_out;

    // Workspace (~94 MB).
    const size_t FULLH = (size_t)(T_ + 1) * BH_ * 2;
    char* ws = (char*)d_ws;
    size_t off = 0;
    __hip_bfloat16* Wih0b = (__hip_bfloat16*)(ws + off); off += (size_t)4 * H_ * P_ * 2;
    __hip_bfloat16* Whh0b = (__hip_bfloat16*)(ws + off); off += (size_t)4 * H_ * H_ * 2;
    __hip_bfloat16* Wih1b = (__hip_bfloat16*)(ws + off); off += (size_t)4 * H_ * H_ * 2;
    __hip_bfloat16* Whh1b = (__hip_bfloat16*)(ws + off); off += (size_t)4 * H_ * H_ * 2;
    __hip_bfloat16* owb   = (__hip_bfloat16*)(ws + off); off += (size_t)P_ * H_ * 2;
    __hip_bfloat16* tseqb = (__hip_bfloat16*)(ws + off); off += (size_t)B_ * T_ * P_ * 2;
    __hip_bfloat16* stokb = (__hip_bfloat16*)(ws + off); off += 256;
    __hip_bfloat16* h1seq = (__hip_bfloat16*)(ws + off); off += FULLH;
    __hip_bfloat16* h2seq = (__hip_bfloat16*)(ws + off); off += FULLH;
    unsigned* cnt         = (unsigned*)(ws + off);       off += (size_t)CNTW * 4;

    auto cvt = [&](const float* s, __hip_bfloat16* d, int n) {
        hipLaunchKernelGGL(cvt_f2b, dim3((n / 4 + 255) / 256), dim3(256), 0, stream, s, d, n);
    };
    cvt(Wih0, Wih0b, 4 * H_ * P_);
    cvt(Whh0, Whh0b, 4 * H_ * H_);
    cvt(Wih1, Wih1b, 4 * H_ * H_);
    cvt(Whh1, Whh1b, 4 * H_ * H_);
    cvt(ow,   owb,   P_ * H_);
    cvt(tseq, tseqb, B_ * T_ * P_);
    cvt(stok, stokb, P_);

    // h0 into the t=-1 slots; init sync words (slot0 flags preset).
    hipLaunchKernelGGL(h0_kernel, dim3(256), dim3(256), 0, stream,
                       z, fw, fb, h1seq, h2seq, cnt);

    PParams pp;
    pp.tseqb = tseqb; pp.stokb = stokb;
    pp.Wih0b = Wih0b; pp.Whh0b = Whh0b; pp.Wih1b = Wih1b; pp.Whh1b = Whh1b;
    pp.owb = owb;
    pp.bih0 = bih0; pp.bhh0 = bhh0; pp.bih1 = bih1; pp.bhh1 = bhh1; pp.ob = ob;
    pp.h1seq = h1seq; pp.h2seq = h2seq;
    pp.out = out;
    pp.cnt = cnt;

    hipFuncSetAttribute((const void*)lstm_persistent,
                        hipFuncAttributeMaxDynamicSharedMemorySize, LDS_TOTAL);
    void* args[] = { &pp };
    hipLaunchCooperativeKernel((void*)lstm_persistent, dim3(256), dim3(512),
                               args, LDS_TOTAL, stream);
}